// Round 19
// baseline (232.677 us; speedup 1.0000x reference)
//
#include <hip/hip_runtime.h>
#include <hip/hip_bf16.h>
#include <math.h>

#define NB 4
#define NC 16
#define NN 8192
#define NK 9
#define CANDN 128          /* per-row survivor cap (R14-verified regime) */
#define MR (NN / 4)        /* m-range per wave (4 waves per block) */
#define HPAD 129           /* hist row stride; MUST be > 127 bins (R17 lesson) */
#define NROW 64            /* rows per block = 4 n-tiles of 16 */

typedef short s16x8 __attribute__((ext_vector_type(8)));
typedef float f32x4 __attribute__((ext_vector_type(4)));

// ws layout (bytes)
#define OFF_XS   2097152u
#define OFF_NS   4194304u
#define OFF_NK   4325376u
#define OFF_NBR  4456448u
#define OFF_FLAG 5046272u
#define OFF_CAND 5177344u   /* + 32768*128*2 = 13565952 total (< proven ws 14.9MB) */

// ---------------------------------------------------------------------------
// Kernel 0: EXACT R14 prep. xt = transposed f32; ns32 = numpy-replica norm
// (verified R3); nk = 128+0.5*ns; xs = bf16 hi/lo split [m][hi*16,lo*16].
// ---------------------------------------------------------------------------
__global__ void prep_kernel(const float* __restrict__ x,
                            float* __restrict__ xt,
                            float* __restrict__ ns32,
                            float* __restrict__ nk,
                            unsigned short* __restrict__ xs) {
    int t = blockIdx.x * 256 + threadIdx.x;   // 0..32767
    int b = t >> 13, m = t & (NN - 1);
    const float* xb = x + (size_t)b * NC * NN;
    float v[NC];
#pragma unroll
    for (int c = 0; c < NC; ++c) v[c] = xb[(size_t)c * NN + m];  // coalesced
    float s = __fmul_rn(v[0], v[0]);
#pragma unroll
    for (int c = 1; c < NC; ++c) s = __fadd_rn(s, __fmul_rn(v[c], v[c]));
    float* o = xt + (size_t)t * NC;
#pragma unroll
    for (int c = 0; c < NC; ++c) o[c] = v[c];
    ns32[t] = s;
    nk[t] = 128.0f + 0.5f * s;
    unsigned short* xo = xs + (size_t)t * 32;
#pragma unroll
    for (int c = 0; c < NC; ++c) {
        __hip_bfloat16 h = __float2bfloat16(v[c]);
        float hf = __bfloat162float(h);
        __hip_bfloat16 l = __float2bfloat16(v[c] - hf);
        xo[c] = *(unsigned short*)&h;
        xo[16 + c] = *(unsigned short*)&l;
    }
}

__device__ __forceinline__ s16x8 negbf(s16x8 v) {   // bf16 sign flip
    s16x8 r;
#pragma unroll
    for (int i = 0; i < 8; ++i) r[i] = (short)(v[i] ^ (short)0x8000);
    return r;
}

// ---------------------------------------------------------------------------
// Kernel 1: R14's verified selection logic over 64-ROW blocks (4 n-tiles per
// wave). Rationale (R18 counters): topk is vector-load bound — each A/nk
// load-pair (2 KB/wave) must serve as many keys as possible. R18 = 4
// keys/lane/load (3.2 GB chip-wide); R14 = 8; here 16 (0.8 GB). Per-row
// statistics byte-identical to R14/R18: B from the same 4096-m subset
// (4 waves x first 1024 of each 2048-m quarter), 0.25-key bins, scan
// 0..126, accept acc < (base8+B+1.25)/8 over full 8192, cap 128,
// single-owner plain-store flags. Superset proof unchanged. Grid 512 =
// 2 blocks/CU (LDS ~50 KB); low occupancy is deliberate — per-iter ILP
// (4 indep MFMA chains + 16 filter ops) covers latency.
// ---------------------------------------------------------------------------
__global__ __launch_bounds__(256, 2) void topk_kernel(
        const unsigned short* __restrict__ xs, const float* __restrict__ nk,
        unsigned short* __restrict__ cand, unsigned* __restrict__ flags) {
    __shared__ __align__(16) unsigned hist[NROW * HPAD];       // 33 KB
    __shared__ __align__(16) unsigned short list[NROW][CANDN]; // 16 KB
    __shared__ unsigned cnt[NROW];
    __shared__ unsigned Bbin[NROW];
    const int tid = threadIdx.x;
    const int L = tid & 63;
    const int wq = tid >> 6;                 // wave id 0..3 = m-quarter
    const int b = blockIdx.x >> 7;           // batch (grid 512 = 4 x 128)
    const int n0 = (blockIdx.x & 127) * NROW; // block's 64-row group
    const int lrow = L & 15;
    const int lk = L >> 4;                   // 0..3

    {   // LDS init (incl. list sentinels)
        for (int i = tid; i < NROW * HPAD; i += 256) hist[i] = 0u;
        unsigned* lp = (unsigned*)&list[0][0];
        for (int i = tid; i < NROW * CANDN / 2; i += 256) lp[i] = 0xFFFFFFFFu;
        if (tid < NROW) { cnt[tid] = 0u; Bbin[tid] = 127u; }
    }
    __syncthreads();

    const char* xsb = (const char*)xs + (size_t)b * NN * 64;
    const float* nkb = nk + (size_t)b * NN;
    const char* nkc = (const char*)nkb;

    // B fragments (negated) for the block's FOUR 16-row tiles (R9-verified).
    const int khalf = (lk & 1) * 16;
    s16x8 bhi[4], blo[4];
    float base8[4];
#pragma unroll
    for (int nt = 0; nt < 4; ++nt) {
        const int rr = n0 + nt * 16 + lrow;
        bhi[nt] = negbf(*(const s16x8*)(xsb + (size_t)rr * 64 + khalf));
        blo[nt] = negbf(*(const s16x8*)(xsb + (size_t)rr * 64 + 32 + khalf));
        base8[nt] = 8.0f * (256.0f - nkb[rr]);   // 8 * (key at dist 0)
    }

    const int m0 = wq * MR;                  // wave's 2048-m quarter
    const int voffA0 = (m0 + lrow) * 64 + lk * 16;
    const int voffK0 = (m0 + lk * 4) * 4;

    // ---- Pass 1: histogram over the wave's first 1024 m's (1/2 subset) ----
    {
        int vA = voffA0, vK = voffK0;
        for (int t = 0; t < 64; ++t) {
            const s16x8 a = *(const s16x8*)(xsb + vA);
            const f32x4 nkv = *(const f32x4*)(nkc + vK);
#pragma unroll
            for (int nt = 0; nt < 4; ++nt) {
                f32x4 acc = __builtin_amdgcn_mfma_f32_16x16x32_bf16(a, bhi[nt], nkv, 0, 0, 0);
                acc = __builtin_amdgcn_mfma_f32_16x16x32_bf16(a, blo[nt], acc, 0, 0, 0);
                const int hrow = nt * 16 + lrow;
#pragma unroll
                for (int r = 0; r < 4; ++r) {
                    const float rr = fmaf(acc[r], 8.0f, -base8[nt]);
                    if (rr < 127.0f) {  // bin 127 never read by the scan
                        const unsigned bin = (unsigned)fmaxf(rr, 0.0f);
                        atomicAdd(&hist[hrow * HPAD + bin], 1u);
                    }
                }
            }
            vA += 1024;
            vK += 64;
        }
    }
    __syncthreads();
    if (tid < NROW) {   // scan: first bin (0..126) with cum >= 12
        unsigned cum = 0;
        unsigned Bv = 127u;
        for (int j = 0; j < 127; ++j) {
            cum += hist[tid * HPAD + j];
            if (cum >= 12u) { Bv = (unsigned)j; break; }
        }
        Bbin[tid] = Bv;
    }
    __syncthreads();
    float thrf[4];
#pragma unroll
    for (int nt = 0; nt < 4; ++nt)
        thrf[nt] = (base8[nt] + (float)Bbin[nt * 16 + lrow] + 1.25f) * 0.125f;

    // ---- Pass 2: full 2048-m scan, min-tree gate + rare predicated push ----
    {
        int vA = voffA0, vK = voffK0;
        for (int t = 0; t < MR / 16; ++t) {
            const s16x8 a = *(const s16x8*)(xsb + vA);
            const f32x4 nkv = *(const f32x4*)(nkc + vK);
#pragma unroll
            for (int nt = 0; nt < 4; ++nt) {
                f32x4 acc = __builtin_amdgcn_mfma_f32_16x16x32_bf16(a, bhi[nt], nkv, 0, 0, 0);
                acc = __builtin_amdgcn_mfma_f32_16x16x32_bf16(a, blo[nt], acc, 0, 0, 0);
                const float mn = fminf(fminf(acc[0], acc[1]),
                                       fminf(acc[2], acc[3]));
                if (mn < thrf[nt]) {
                    const int hrow = nt * 16 + lrow;
#pragma unroll
                    for (int r = 0; r < 4; ++r) {
                        if (acc[r] < thrf[nt]) {
                            const unsigned m =
                                (unsigned)(m0 + t * 16 + lk * 4 + r);
                            const unsigned idx = atomicAdd(&cnt[hrow], 1u);
                            if (idx < CANDN)
                                list[hrow][idx] = (unsigned short)m;
                        }
                    }
                }
            }
            vA += 1024;
            vK += 64;
        }
    }
    __syncthreads();

    // dump survivors (bulk, coalesced): 64 rows x 256B = 16KB in 4 passes
#pragma unroll
    for (int p = 0; p < 4; ++p) {
        const int rr = (tid >> 4) + p * 16;   // row 0..63
        const int seg = tid & 15;
        const unsigned grow = (unsigned)(b * NN + n0 + rr);
        const uint4* src =
            (const uint4*)((const char*)&list[0][0] + rr * 256 + seg * 16);
        uint4* dst = (uint4*)((char*)cand + (size_t)grow * 256 + seg * 16);
        dst[0] = src[0];
    }
    if (tid < NROW) {   // single-owner plain store (R14 semantics)
        const bool bad = (cnt[tid] > (unsigned)CANDN) || (Bbin[tid] == 127u);
        flags[b * NN + n0 + tid] = bad ? 0xFFFFFFFFu : cnt[tid];
    }
}

// ---------------------------------------------------------------------------
// Kernel 2: EXACT R14 rerank. BIT-EXACT numpy-f32 replica (verified R3):
// dot = sequential fmaf chain; dist = fl(fl(ns_n+ns_m)-fl(2*dot)),
// max(dist,0); diag k32=0; stable (dist,idx) order via packed u64.
// 4 threads per row stride the cnt survivors; sorted-9 each; LDS merge.
// ---------------------------------------------------------------------------
__global__ __launch_bounds__(256) void rerank_kernel(
        const float* __restrict__ xt, const float* __restrict__ ns32,
        const unsigned short* __restrict__ cand,
        const unsigned* __restrict__ flags,
        unsigned short* __restrict__ nbr) {
    __shared__ unsigned long long mk[64][36];
    const int tid = threadIdx.x;
    const int lr = tid >> 2;                 // local row 0..63
    const int j = tid & 3;                   // row-segment thread
    const int row = blockIdx.x * 64 + lr;    // 0..32767
    const int b = row >> 13;                 // uniform (64 | 8192)
    const int n = row & (NN - 1);
    const float* xb = xt + (size_t)b * NN * NC;
    const float* xrow = xb + (size_t)n * NC;
    float xv[NC];
#pragma unroll
    for (int c = 0; c < NC; ++c) xv[c] = xrow[c];
    const float nsn = ns32[row];
    const float* nsb = ns32 + b * NN;

    unsigned long long lst[NK];
#pragma unroll
    for (int i = 0; i < NK; ++i) lst[i] = ~0ULL;

    auto consider = [&](int m) {
        const float* col = xb + (size_t)m * NC;
        float dot = 0.0f;
#pragma unroll
        for (int c = 0; c < NC; ++c)
            dot = fmaf(xv[c], col[c], dot);   // npyv_muladd replica (FMA)
        float dist = __fsub_rn(__fadd_rn(nsn, nsb[m]), __fmul_rn(2.0f, dot));
        dist = fmaxf(dist, 0.0f);
        const unsigned k32 = (m == n) ? 0u
                                      : (__float_as_uint(dist) | 0x80000000u);
        unsigned long long key = ((unsigned long long)k32 << 32) | (unsigned)m;
        if (key < lst[NK - 1]) {
#pragma unroll
            for (int i = 0; i < NK; ++i) {
                unsigned long long aa = lst[i];
                bool sm = key < aa;
                unsigned long long lo = sm ? key : aa;
                unsigned long long hi = sm ? aa : key;
                lst[i] = lo;
                key = hi;
            }
        }
    };

    const unsigned nv = flags[row];
    if (nv == 0xFFFFFFFFu) {                 // exact fallback, 4-way split
        for (int m = j * (NN / 4); m < (j + 1) * (NN / 4); ++m) consider(m);
    } else {
        const unsigned short* cl = cand + (size_t)row * CANDN;
        for (unsigned jj = (unsigned)j; jj < nv; jj += 4) consider(cl[jj]);
    }
#pragma unroll
    for (int i = 0; i < NK; ++i) mk[lr][j * NK + i] = lst[i];
    __syncthreads();
    if (j == 0) {
        unsigned long long fin[NK];
#pragma unroll
        for (int i = 0; i < NK; ++i) fin[i] = ~0ULL;
        for (int s = 0; s < 4 * NK; ++s) {
            unsigned long long key = mk[lr][s];
            if (key < fin[NK - 1]) {
#pragma unroll
                for (int i = 0; i < NK; ++i) {
                    unsigned long long aa = fin[i];
                    bool sm = key < aa;
                    unsigned long long lo = sm ? key : aa;
                    unsigned long long hi = sm ? aa : key;
                    fin[i] = lo;
                    key = hi;
                }
            }
        }
        unsigned short* o = nbr + (size_t)row * NK;
#pragma unroll
        for (int k = 0; k < NK; ++k) o[k] = (unsigned short)(fin[k] & 0xFFFFu);
    }
}

// ---------------------------------------------------------------------------
// Kernel 3: EXACT R14 conv. Block-uniform output channel -> scalar W/bias.
// ---------------------------------------------------------------------------
__global__ __launch_bounds__(256) void conv_kernel(
        const float* __restrict__ xt, const unsigned short* __restrict__ nbr,
        const float* __restrict__ W, const float* __restrict__ bias,
        float* __restrict__ out) {
    const int tid = threadIdx.x;
    const int ob = blockIdx.x >> 7;       // 0..15, uniform
    const int rb = blockIdx.x & 127;
    const int row = rb * 256 + tid;
    const int b = rb >> 5;                // uniform
    const int n = row & (NN - 1);
    const float* xb = xt + (size_t)b * NN * NC;
    const float* Wo = W + ob * (NC * NK); // uniform
    const unsigned short* nl = nbr + (size_t)row * NK;

    float acc = bias[ob];
    for (int k = 0; k < NK; ++k) {
        const float* col = xb + (size_t)nl[k] * NC;
        float cv[NC];
#pragma unroll
        for (int c = 0; c < NC; ++c) cv[c] = col[c];
#pragma unroll
        for (int c = 0; c < NC; ++c)
            acc = fmaf(Wo[c * NK + k], cv[c], acc);
    }
    out[(size_t)b * NC * NN + (size_t)ob * NN + n] = acc;
}

extern "C" void kernel_launch(void* const* d_in, const int* in_sizes, int n_in,
                              void* d_out, int out_size, void* d_ws, size_t ws_size,
                              hipStream_t stream) {
    const float* x = (const float*)d_in[0];     // [4][16][8192]
    const float* W = (const float*)d_in[1];     // [16][16][9]
    const float* bias = (const float*)d_in[2];  // [16]
    float* out = (float*)d_out;                 // [4][16][8192]

    char* ws = (char*)d_ws;
    float* xt = (float*)ws;
    unsigned short* xs = (unsigned short*)(ws + OFF_XS);
    float* ns32 = (float*)(ws + OFF_NS);
    float* nk = (float*)(ws + OFF_NK);
    unsigned short* nbr = (unsigned short*)(ws + OFF_NBR);
    unsigned* flags = (unsigned*)(ws + OFF_FLAG);
    unsigned short* cand = (unsigned short*)(ws + OFF_CAND);

    prep_kernel<<<128, 256, 0, stream>>>(x, xt, ns32, nk, xs);
    topk_kernel<<<512, 256, 0, stream>>>(xs, nk, cand, flags);
    rerank_kernel<<<512, 256, 0, stream>>>(xt, ns32, cand, flags, nbr);
    conv_kernel<<<2048, 256, 0, stream>>>(xt, nbr, W, bias, out);
}

// Round 20
// 171.335 us; speedup vs baseline: 1.3580x; 1.3580x over previous
//
#include <hip/hip_runtime.h>
#include <hip/hip_bf16.h>
#include <math.h>

#define NB 4
#define NC 16
#define NN 8192
#define NK 9
#define CANDN 128          /* per-row survivor cap (R14-verified regime) */
#define MR (NN / 4)        /* m-range per wave (4 waves per block) */
#define HPAD 129           /* hist row stride; MUST be > 127 bins (R17 lesson) */

typedef short s16x8 __attribute__((ext_vector_type(8)));
typedef float f32x4 __attribute__((ext_vector_type(4)));

// ws layout (bytes)
#define OFF_XS   2097152u
#define OFF_NS   4194304u
#define OFF_NK   4325376u
#define OFF_NBR  4456448u
#define OFF_FLAG 5046272u
#define OFF_CAND 5177344u   /* + 32768*128*2 = 13565952 total (< proven ws 14.9MB) */

// ---------------------------------------------------------------------------
// Kernel 0: EXACT R14 prep. xt = transposed f32; ns32 = numpy-replica norm
// (verified R3); nk = 128+0.5*ns; xs = bf16 hi/lo split [m][hi*16,lo*16].
// ---------------------------------------------------------------------------
__global__ void prep_kernel(const float* __restrict__ x,
                            float* __restrict__ xt,
                            float* __restrict__ ns32,
                            float* __restrict__ nk,
                            unsigned short* __restrict__ xs) {
    int t = blockIdx.x * 256 + threadIdx.x;   // 0..32767
    int b = t >> 13, m = t & (NN - 1);
    const float* xb = x + (size_t)b * NC * NN;
    float v[NC];
#pragma unroll
    for (int c = 0; c < NC; ++c) v[c] = xb[(size_t)c * NN + m];  // coalesced
    float s = __fmul_rn(v[0], v[0]);
#pragma unroll
    for (int c = 1; c < NC; ++c) s = __fadd_rn(s, __fmul_rn(v[c], v[c]));
    float* o = xt + (size_t)t * NC;
#pragma unroll
    for (int c = 0; c < NC; ++c) o[c] = v[c];
    ns32[t] = s;
    nk[t] = 128.0f + 0.5f * s;
    unsigned short* xo = xs + (size_t)t * 32;
#pragma unroll
    for (int c = 0; c < NC; ++c) {
        __hip_bfloat16 h = __float2bfloat16(v[c]);
        float hf = __bfloat162float(h);
        __hip_bfloat16 l = __float2bfloat16(v[c] - hf);
        xo[c] = *(unsigned short*)&h;
        xo[16 + c] = *(unsigned short*)&l;
    }
}

__device__ __forceinline__ s16x8 negbf(s16x8 v) {   // bf16 sign flip
    s16x8 r;
#pragma unroll
    for (int i = 0; i < 8; ++i) r[i] = (short)(v[i] ^ (short)0x8000);
    return r;
}

// ---------------------------------------------------------------------------
// Kernel 1: EXACT R14 topk (best measured config: 32-row groups, 2 n-tiles
// per wave, grid 1024, 4 blocks/CU) + ONE bit-exact change: 1-deep register
// PREFETCH of next iteration's a/nkv in both passes. R18/R19 swept rows/block
// {16,64} -> both slower; R14's latency exposure (381 cyc/wave-iter vs ~100
// issued) is attacked here by issuing t+1's loads before t's MFMAs (waitcnt
// lands after ~4 MFMA + filter, x4 waves/SIMD covers ~L2 latency). Same
// arithmetic, same order, same outputs. Last-iter address clamped (no OOB).
// ---------------------------------------------------------------------------
__global__ __launch_bounds__(256, 4) void topk_kernel(
        const unsigned short* __restrict__ xs, const float* __restrict__ nk,
        unsigned short* __restrict__ cand, unsigned* __restrict__ flags) {
    __shared__ __align__(16) unsigned hist[32 * HPAD];       // 16.5 KB
    __shared__ __align__(16) unsigned short list[32][CANDN]; // 8 KB
    __shared__ unsigned cnt[32];
    __shared__ unsigned Bbin[32];
    const int tid = threadIdx.x;
    const int L = tid & 63;
    const int q = tid >> 6;                 // wave id = m-quarter
    const int b = blockIdx.x >> 8;          // batch
    const int n0 = (blockIdx.x & 255) * 32; // block's 32-row group
    const int lrow = L & 15;
    const int lk = L >> 4;                  // 0..3

    {   // LDS init (incl. list sentinels)
        for (int i = tid; i < 32 * HPAD; i += 256) hist[i] = 0u;
        unsigned* lp = (unsigned*)&list[0][0];
        for (int i = tid; i < 32 * CANDN / 2; i += 256) lp[i] = 0xFFFFFFFFu;
        if (tid < 32) { cnt[tid] = 0u; Bbin[tid] = 127u; }
    }
    __syncthreads();

    const char* xsb = (const char*)xs + (size_t)b * NN * 64;
    const float* nkb = nk + (size_t)b * NN;
    const char* nkc = (const char*)nkb;

    // B fragments (negated) for the wave's two 16-row tiles (R9-verified).
    const int khalf = (lk & 1) * 16;
    const int r0 = n0 + lrow, r1 = n0 + 16 + lrow;
    const s16x8 bhi0 = negbf(*(const s16x8*)(xsb + (size_t)r0 * 64 + khalf));
    const s16x8 blo0 = negbf(*(const s16x8*)(xsb + (size_t)r0 * 64 + 32 + khalf));
    const s16x8 bhi1 = negbf(*(const s16x8*)(xsb + (size_t)r1 * 64 + khalf));
    const s16x8 blo1 = negbf(*(const s16x8*)(xsb + (size_t)r1 * 64 + 32 + khalf));

    const float base8_0 = 8.0f * (256.0f - nkb[r0]);  // 8 * (key at dist 0)
    const float base8_1 = 8.0f * (256.0f - nkb[r1]);

    const int m0 = q * MR;
    const int voffA0 = (m0 + lrow) * 64 + lk * 16;
    const int voffK0 = (m0 + lk * 4) * 4;

    // ---- Pass 1: histogram over the wave's first 1024 m's (1/2 subset) ----
    {
        int vA = voffA0, vK = voffK0;
        s16x8 a = *(const s16x8*)(xsb + vA);
        f32x4 nkv = *(const f32x4*)(nkc + vK);
        for (int t = 0; t < 64; ++t) {
            const int adv = (t < 63) ? 1 : 0;            // clamp last iter
            const s16x8 a_n = *(const s16x8*)(xsb + vA + adv * 1024);
            const f32x4 nkv_n = *(const f32x4*)(nkc + vK + adv * 64);
            f32x4 acc0 = __builtin_amdgcn_mfma_f32_16x16x32_bf16(a, bhi0, nkv, 0, 0, 0);
            acc0 = __builtin_amdgcn_mfma_f32_16x16x32_bf16(a, blo0, acc0, 0, 0, 0);
            f32x4 acc1 = __builtin_amdgcn_mfma_f32_16x16x32_bf16(a, bhi1, nkv, 0, 0, 0);
            acc1 = __builtin_amdgcn_mfma_f32_16x16x32_bf16(a, blo1, acc1, 0, 0, 0);
#pragma unroll
            for (int r = 0; r < 4; ++r) {
                const float rr = fmaf(acc0[r], 8.0f, -base8_0);
                if (rr < 127.0f) {      // bin 127 never read by the scan
                    const unsigned bin = (unsigned)fmaxf(rr, 0.0f);
                    atomicAdd(&hist[lrow * HPAD + bin], 1u);
                }
            }
#pragma unroll
            for (int r = 0; r < 4; ++r) {
                const float rr = fmaf(acc1[r], 8.0f, -base8_1);
                if (rr < 127.0f) {
                    const unsigned bin = (unsigned)fmaxf(rr, 0.0f);
                    atomicAdd(&hist[(16 + lrow) * HPAD + bin], 1u);
                }
            }
            a = a_n;
            nkv = nkv_n;
            vA += 1024;
            vK += 64;
        }
    }
    __syncthreads();
    if (tid < 32) {   // scan: first bin (0..126) with cum >= 12
        unsigned cum = 0;
        unsigned Bv = 127u;
        for (int j = 0; j < 127; ++j) {
            cum += hist[tid * HPAD + j];
            if (cum >= 12u) { Bv = (unsigned)j; break; }
        }
        Bbin[tid] = Bv;
    }
    __syncthreads();
    const unsigned B0 = Bbin[lrow], B1 = Bbin[16 + lrow];
    const float thrf0 = (base8_0 + (float)B0 + 1.25f) * 0.125f;
    const float thrf1 = (base8_1 + (float)B1 + 1.25f) * 0.125f;

    // ---- Pass 2: full scan, min-tree gate + rare predicated push ----
    {
        int vA = voffA0, vK = voffK0;
        s16x8 a = *(const s16x8*)(xsb + vA);
        f32x4 nkv = *(const f32x4*)(nkc + vK);
        for (int t = 0; t < MR / 16; ++t) {
            const int adv = (t < MR / 16 - 1) ? 1 : 0;   // clamp last iter
            const s16x8 a_n = *(const s16x8*)(xsb + vA + adv * 1024);
            const f32x4 nkv_n = *(const f32x4*)(nkc + vK + adv * 64);
            f32x4 acc0 = __builtin_amdgcn_mfma_f32_16x16x32_bf16(a, bhi0, nkv, 0, 0, 0);
            acc0 = __builtin_amdgcn_mfma_f32_16x16x32_bf16(a, blo0, acc0, 0, 0, 0);
            f32x4 acc1 = __builtin_amdgcn_mfma_f32_16x16x32_bf16(a, bhi1, nkv, 0, 0, 0);
            acc1 = __builtin_amdgcn_mfma_f32_16x16x32_bf16(a, blo1, acc1, 0, 0, 0);
            const float mn0 = fminf(fminf(acc0[0], acc0[1]),
                                    fminf(acc0[2], acc0[3]));
            if (mn0 < thrf0) {
#pragma unroll
                for (int r = 0; r < 4; ++r) {
                    if (acc0[r] < thrf0) {
                        const unsigned m =
                            (unsigned)(m0 + t * 16 + lk * 4 + r);
                        const unsigned idx = atomicAdd(&cnt[lrow], 1u);
                        if (idx < CANDN)
                            list[lrow][idx] = (unsigned short)m;
                    }
                }
            }
            const float mn1 = fminf(fminf(acc1[0], acc1[1]),
                                    fminf(acc1[2], acc1[3]));
            if (mn1 < thrf1) {
#pragma unroll
                for (int r = 0; r < 4; ++r) {
                    if (acc1[r] < thrf1) {
                        const unsigned m =
                            (unsigned)(m0 + t * 16 + lk * 4 + r);
                        const unsigned idx = atomicAdd(&cnt[16 + lrow], 1u);
                        if (idx < CANDN)
                            list[16 + lrow][idx] = (unsigned short)m;
                    }
                }
            }
            a = a_n;
            nkv = nkv_n;
            vA += 1024;
            vK += 64;
        }
    }
    __syncthreads();

    // dump survivors (bulk, coalesced) + flags (= cnt, or ~0 -> fallback)
    {
        const int rr = tid >> 3, seg = tid & 7;
        const unsigned grow = (unsigned)(b * NN + n0 + rr);
        const uint4* src =
            (const uint4*)((const char*)&list[0][0] + rr * 256 + seg * 32);
        uint4* dst = (uint4*)((char*)cand + (size_t)grow * 256 + seg * 32);
        dst[0] = src[0];
        dst[1] = src[1];
    }
    if (tid < 32) {
        const bool bad = (cnt[tid] > (unsigned)CANDN) || (Bbin[tid] == 127u);
        flags[b * NN + n0 + tid] = bad ? 0xFFFFFFFFu : cnt[tid];
    }
}

// ---------------------------------------------------------------------------
// Kernel 2: EXACT R14 rerank. BIT-EXACT numpy-f32 replica (verified R3):
// dot = sequential fmaf chain; dist = fl(fl(ns_n+ns_m)-fl(2*dot)),
// max(dist,0); diag k32=0; stable (dist,idx) order via packed u64.
// 4 threads per row stride the cnt survivors; sorted-9 each; LDS merge.
// ---------------------------------------------------------------------------
__global__ __launch_bounds__(256) void rerank_kernel(
        const float* __restrict__ xt, const float* __restrict__ ns32,
        const unsigned short* __restrict__ cand,
        const unsigned* __restrict__ flags,
        unsigned short* __restrict__ nbr) {
    __shared__ unsigned long long mk[64][36];
    const int tid = threadIdx.x;
    const int lr = tid >> 2;                 // local row 0..63
    const int j = tid & 3;                   // row-segment thread
    const int row = blockIdx.x * 64 + lr;    // 0..32767
    const int b = row >> 13;                 // uniform (64 | 8192)
    const int n = row & (NN - 1);
    const float* xb = xt + (size_t)b * NN * NC;
    const float* xrow = xb + (size_t)n * NC;
    float xv[NC];
#pragma unroll
    for (int c = 0; c < NC; ++c) xv[c] = xrow[c];
    const float nsn = ns32[row];
    const float* nsb = ns32 + b * NN;

    unsigned long long lst[NK];
#pragma unroll
    for (int i = 0; i < NK; ++i) lst[i] = ~0ULL;

    auto consider = [&](int m) {
        const float* col = xb + (size_t)m * NC;
        float dot = 0.0f;
#pragma unroll
        for (int c = 0; c < NC; ++c)
            dot = fmaf(xv[c], col[c], dot);   // npyv_muladd replica (FMA)
        float dist = __fsub_rn(__fadd_rn(nsn, nsb[m]), __fmul_rn(2.0f, dot));
        dist = fmaxf(dist, 0.0f);
        const unsigned k32 = (m == n) ? 0u
                                      : (__float_as_uint(dist) | 0x80000000u);
        unsigned long long key = ((unsigned long long)k32 << 32) | (unsigned)m;
        if (key < lst[NK - 1]) {
#pragma unroll
            for (int i = 0; i < NK; ++i) {
                unsigned long long aa = lst[i];
                bool sm = key < aa;
                unsigned long long lo = sm ? key : aa;
                unsigned long long hi = sm ? aa : key;
                lst[i] = lo;
                key = hi;
            }
        }
    };

    const unsigned nv = flags[row];
    if (nv == 0xFFFFFFFFu) {                 // exact fallback, 4-way split
        for (int m = j * (NN / 4); m < (j + 1) * (NN / 4); ++m) consider(m);
    } else {
        const unsigned short* cl = cand + (size_t)row * CANDN;
        for (unsigned jj = (unsigned)j; jj < nv; jj += 4) consider(cl[jj]);
    }
#pragma unroll
    for (int i = 0; i < NK; ++i) mk[lr][j * NK + i] = lst[i];
    __syncthreads();
    if (j == 0) {
        unsigned long long fin[NK];
#pragma unroll
        for (int i = 0; i < NK; ++i) fin[i] = ~0ULL;
        for (int s = 0; s < 4 * NK; ++s) {
            unsigned long long key = mk[lr][s];
            if (key < fin[NK - 1]) {
#pragma unroll
                for (int i = 0; i < NK; ++i) {
                    unsigned long long aa = fin[i];
                    bool sm = key < aa;
                    unsigned long long lo = sm ? key : aa;
                    unsigned long long hi = sm ? aa : key;
                    fin[i] = lo;
                    key = hi;
                }
            }
        }
        unsigned short* o = nbr + (size_t)row * NK;
#pragma unroll
        for (int k = 0; k < NK; ++k) o[k] = (unsigned short)(fin[k] & 0xFFFFu);
    }
}

// ---------------------------------------------------------------------------
// Kernel 3: EXACT R14 conv. Block-uniform output channel -> scalar W/bias.
// ---------------------------------------------------------------------------
__global__ __launch_bounds__(256) void conv_kernel(
        const float* __restrict__ xt, const unsigned short* __restrict__ nbr,
        const float* __restrict__ W, const float* __restrict__ bias,
        float* __restrict__ out) {
    const int tid = threadIdx.x;
    const int ob = blockIdx.x >> 7;       // 0..15, uniform
    const int rb = blockIdx.x & 127;
    const int row = rb * 256 + tid;
    const int b = rb >> 5;                // uniform
    const int n = row & (NN - 1);
    const float* xb = xt + (size_t)b * NN * NC;
    const float* Wo = W + ob * (NC * NK); // uniform
    const unsigned short* nl = nbr + (size_t)row * NK;

    float acc = bias[ob];
    for (int k = 0; k < NK; ++k) {
        const float* col = xb + (size_t)nl[k] * NC;
        float cv[NC];
#pragma unroll
        for (int c = 0; c < NC; ++c) cv[c] = col[c];
#pragma unroll
        for (int c = 0; c < NC; ++c)
            acc = fmaf(Wo[c * NK + k], cv[c], acc);
    }
    out[(size_t)b * NC * NN + (size_t)ob * NN + n] = acc;
}

extern "C" void kernel_launch(void* const* d_in, const int* in_sizes, int n_in,
                              void* d_out, int out_size, void* d_ws, size_t ws_size,
                              hipStream_t stream) {
    const float* x = (const float*)d_in[0];     // [4][16][8192]
    const float* W = (const float*)d_in[1];     // [16][16][9]
    const float* bias = (const float*)d_in[2];  // [16]
    float* out = (float*)d_out;                 // [4][16][8192]

    char* ws = (char*)d_ws;
    float* xt = (float*)ws;
    unsigned short* xs = (unsigned short*)(ws + OFF_XS);
    float* ns32 = (float*)(ws + OFF_NS);
    float* nk = (float*)(ws + OFF_NK);
    unsigned short* nbr = (unsigned short*)(ws + OFF_NBR);
    unsigned* flags = (unsigned*)(ws + OFF_FLAG);
    unsigned short* cand = (unsigned short*)(ws + OFF_CAND);

    prep_kernel<<<128, 256, 0, stream>>>(x, xt, ns32, nk, xs);
    topk_kernel<<<1024, 256, 0, stream>>>(xs, nk, cand, flags);
    rerank_kernel<<<512, 256, 0, stream>>>(xt, ns32, cand, flags, nbr);
    conv_kernel<<<2048, 256, 0, stream>>>(xt, nbr, W, bias, out);
}